// Round 1
// baseline (5727.308 us; speedup 1.0000x reference)
//
#include <hip/hip_runtime.h>
#include <hip/hip_bf16.h>
#include <cstdint>
#include <cstddef>

// MoE MLP: T=8192 tokens, D=2048, I=5632, 8 experts top-2 + shared MLP.
// Strategy: route tokens -> compacted per-expert row lists (shared MLP =
// "expert 8", weight 1.0, all tokens) -> grouped bf16 MFMA GEMMs:
//   GEMM1: h[r][i] = silu(x@gate^T) * (x@up^T)   (gate+up fused, h bf16)
//   GEMM2: out[tok] += w_r * (h[r] @ down^T)     (atomicAdd scatter)
// Workspace use: ~297 MB (control 0.5MB + x_bf16 33.5MB + h 277MB).

#define NUM_EXPERTS 8
#define D_DIM 2048
#define I_DIM 5632
#define T_TOK 8192
#define R_TOT 24576  // 2*T (routed) + T (shared)

typedef __attribute__((ext_vector_type(4))) float f32x4;
typedef __attribute__((ext_vector_type(8))) short short8;

__device__ inline unsigned short f2bf_rne(float f) {
  union { float f; unsigned u; } v; v.f = f;
  unsigned r = v.u + 0x7FFFu + ((v.u >> 16) & 1u);
  return (unsigned short)(r >> 16);
}

// async global->LDS, 16B per lane. LDS side must be wave-uniform base + lane*16.
__device__ inline void gload_lds16(const void* g, void* l) {
  __builtin_amdgcn_global_load_lds(
      (const __attribute__((address_space(1))) unsigned int*)g,
      (__attribute__((address_space(3))) unsigned int*)l, 16, 0, 0);
}

// ---------------- x fp32 -> bf16 ----------------
__global__ __launch_bounds__(256) void xcvt_kernel(const float* __restrict__ x,
                                                   unsigned short* __restrict__ xb) {
  int i = blockIdx.x * 256 + threadIdx.x;  // over float4 groups, exact
  f32x4 v = ((const f32x4*)x)[i];
  ushort4 o;
  o.x = f2bf_rne(v[0]); o.y = f2bf_rne(v[1]);
  o.z = f2bf_rne(v[2]); o.w = f2bf_rne(v[3]);
  ((ushort4*)xb)[i] = o;
}

// ---------------- router ----------------
__global__ __launch_bounds__(256) void router_kernel(
    const float* __restrict__ x, const float* __restrict__ gw,
    int* __restrict__ cnt, float* __restrict__ probsum,
    int* __restrict__ top_e, int* __restrict__ top_pos, float* __restrict__ top_w) {
  __shared__ float red[256 * 8];
  int t = blockIdx.x, tid = threadIdx.x;
  const float* xr = x + (size_t)t * D_DIM;
  float acc[8] = {0.f,0.f,0.f,0.f,0.f,0.f,0.f,0.f};
  for (int d = tid; d < D_DIM; d += 256) {
    float xv = xr[d];
#pragma unroll
    for (int e = 0; e < 8; e++) acc[e] += xv * gw[e * D_DIM + d];
  }
#pragma unroll
  for (int e = 0; e < 8; e++) red[tid * 8 + e] = acc[e];
  __syncthreads();
  for (int s = 128; s > 0; s >>= 1) {
    if (tid < s) {
#pragma unroll
      for (int e = 0; e < 8; e++) red[tid * 8 + e] += red[(tid + s) * 8 + e];
    }
    __syncthreads();
  }
  if (tid == 0) {
    float lg[8];
#pragma unroll
    for (int e = 0; e < 8; e++) lg[e] = red[e];
    // full softmax for aux loss (fp32, matches reference)
    float mx = lg[0];
    for (int e = 1; e < 8; e++) mx = fmaxf(mx, lg[e]);
    float p[8], sum = 0.f;
    for (int e = 0; e < 8; e++) { p[e] = __expf(lg[e] - mx); sum += p[e]; }
    float inv = 1.f / sum;
    for (int e = 0; e < 8; e++) atomicAdd(&probsum[e], p[e] * inv);
    // top-2 (ties -> lower index, matches lax.top_k)
    int i0 = 0;
    for (int e = 1; e < 8; e++) if (lg[e] > lg[i0]) i0 = e;
    int i1 = (i0 == 0) ? 1 : 0;
    for (int e = 0; e < 8; e++) if (e != i0 && lg[e] > lg[i1]) i1 = e;
    float w0 = 1.f / (1.f + __expf(lg[i1] - lg[i0]));  // softmax over (v0,v1)
    float w1 = 1.f - w0;
    int p0 = atomicAdd(&cnt[i0], 1);
    int p1 = atomicAdd(&cnt[i1], 1);
    top_e[t * 2] = i0;     top_pos[t * 2] = p0;     top_w[t * 2] = w0;
    top_e[t * 2 + 1] = i1; top_pos[t * 2 + 1] = p1; top_w[t * 2 + 1] = w1;
  }
}

// ---------------- offsets + aux loss ----------------
__global__ void finalize_kernel(int* __restrict__ cnt, const float* __restrict__ probsum,
                                int* __restrict__ offsets, float* __restrict__ out_aux) {
  if (threadIdx.x == 0) {
    cnt[8] = T_TOK;  // shared pseudo-expert
    int off = 0;
    for (int e = 0; e < 9; e++) { offsets[e] = off; off += cnt[e]; }
    offsets[9] = off;  // == R_TOT
    float s = 0.f;
    for (int e = 0; e < 8; e++)
      s += ((float)cnt[e] / (float)T_TOK) * (probsum[e] / (float)T_TOK);
    out_aux[0] = 0.01f * s * 8.f;
  }
}

// ---------------- build compacted row lists ----------------
__global__ __launch_bounds__(256) void scatter_kernel(
    const int* __restrict__ top_e, const int* __restrict__ top_pos,
    const float* __restrict__ top_w, const int* __restrict__ offsets,
    int* __restrict__ row_token, float* __restrict__ row_weight) {
  int t = blockIdx.x * 256 + threadIdx.x;
  if (t >= T_TOK) return;
#pragma unroll
  for (int k = 0; k < 2; k++) {
    int e = top_e[t * 2 + k];
    int r = offsets[e] + top_pos[t * 2 + k];
    row_token[r] = t; row_weight[r] = top_w[t * 2 + k];
  }
  int r = offsets[8] + t;
  row_token[r] = t; row_weight[r] = 1.0f;
}

// ---------------- GEMM1: gate+up fused -> h (bf16) ----------------
// block tile 128 rows x 128 I-cols, BK=32, 4 waves in 2x2, each 64x64 via
// 4x4 grid of 16x16x32 bf16 MFMA. Two accumulators (gate, up).
__global__ __launch_bounds__(256, 2) void gemm_gateup(
    const float* __restrict__ expert_gate, const float* __restrict__ expert_up,
    const float* __restrict__ shared_gate, const float* __restrict__ shared_up,
    const unsigned short* __restrict__ xb,
    const int* __restrict__ row_token, const int* __restrict__ offsets,
    unsigned short* __restrict__ h) {
  int e = blockIdx.z;
  int r0 = offsets[e];
  int cnt = offsets[e + 1] - r0;
  int rt = blockIdx.y;
  if (rt * 128 >= cnt) return;
  int ct = blockIdx.x;  // 0..43 over I

  const float* gatep = (e < NUM_EXPERTS) ? expert_gate + (size_t)e * I_DIM * D_DIM : shared_gate;
  const float* upp   = (e < NUM_EXPERTS) ? expert_up   + (size_t)e * I_DIM * D_DIM : shared_up;

  __shared__ __align__(16) unsigned short As[128 * 32];
  __shared__ __align__(16) unsigned short Bg[128 * 32];
  __shared__ __align__(16) unsigned short Bu[128 * 32];

  int tid = threadIdx.x;
  int lane = tid & 63;
  int wave = tid >> 6;
  int wm = wave >> 1, wn = wave & 1;

  // A staging via lds-dma: idx = tid and 256+tid over 16B chunks; row=idx>>2
  int arow0 = tid >> 2, seg = tid & 3;
  int tok0 = row_token[r0 + rt * 128 + arow0];        // padded rows read the
  int tok1 = row_token[r0 + rt * 128 + 64 + arow0];   // next expert's rows (valid mem)
  const unsigned short* ag0 = xb + (size_t)tok0 * D_DIM + seg * 8;
  const unsigned short* ag1 = xb + (size_t)tok1 * D_DIM + seg * 8;
  unsigned short* al0 = &As[tid * 8];
  unsigned short* al1 = &As[(256 + tid) * 8];

  // B staging through VGPRs with fp32->bf16 truncate-convert
  const float* bgp[4]; const float* bup[4]; int bso[4];
#pragma unroll
  for (int j = 0; j < 4; j++) {
    int idxB = j * 256 + tid;                 // over 16B(fp32 float4) chunks
    int brow = idxB >> 3, c4 = idxB & 7;
    size_t goff = (size_t)(ct * 128 + brow) * D_DIM + c4 * 4;
    bgp[j] = gatep + goff;
    bup[j] = upp + goff;
    bso[j] = brow * 32 + c4 * 4;              // bf16 elem offset in Bg/Bu
  }

  f32x4 accg[4][4], accu[4][4];
  f32x4 zero4 = {0.f, 0.f, 0.f, 0.f};
#pragma unroll
  for (int i = 0; i < 4; i++)
#pragma unroll
    for (int j = 0; j < 4; j++) { accg[i][j] = zero4; accu[i][j] = zero4; }

  int kq = lane >> 4, ml = lane & 15;

  for (int k0 = 0; k0 < D_DIM; k0 += 32) {
    // prefetch B into regs (no LDS touch) before the barrier
    f32x4 vg[4], vu[4];
#pragma unroll
    for (int j = 0; j < 4; j++) {
      vg[j] = *(const f32x4*)(bgp[j] + k0);
      vu[j] = *(const f32x4*)(bup[j] + k0);
    }
    __syncthreads();  // all waves done reading previous LDS tiles
    gload_lds16(ag0 + k0, al0);
    gload_lds16(ag1 + k0, al1);
#pragma unroll
    for (int j = 0; j < 4; j++) {
      const unsigned* ap = (const unsigned*)&vg[j];
      uint2 w;
      w.x = (ap[1] & 0xFFFF0000u) | (ap[0] >> 16);
      w.y = (ap[3] & 0xFFFF0000u) | (ap[2] >> 16);
      *(uint2*)&Bg[bso[j]] = w;
      ap = (const unsigned*)&vu[j];
      w.x = (ap[1] & 0xFFFF0000u) | (ap[0] >> 16);
      w.y = (ap[3] & 0xFFFF0000u) | (ap[2] >> 16);
      *(uint2*)&Bu[bso[j]] = w;
    }
    __syncthreads();  // drains lds-dma (vmcnt) + ds_writes

    short8 af[4];
#pragma unroll
    for (int i = 0; i < 4; i++)
      af[i] = *(const short8*)&As[(wm * 64 + i * 16 + ml) * 32 + kq * 8];
#pragma unroll
    for (int j = 0; j < 4; j++) {
      int brow = (wn * 64 + j * 16 + ml) * 32 + kq * 8;
      short8 bgf = *(const short8*)&Bg[brow];
      short8 buf = *(const short8*)&Bu[brow];
#pragma unroll
      for (int i = 0; i < 4; i++) {
        accg[i][j] = __builtin_amdgcn_mfma_f32_16x16x32_bf16(af[i], bgf, accg[i][j], 0, 0, 0);
        accu[i][j] = __builtin_amdgcn_mfma_f32_16x16x32_bf16(af[i], buf, accu[i][j], 0, 0, 0);
      }
    }
  }

  // epilogue: h = silu(g)*u, bf16. C/D: col=lane&15, row=(lane>>4)*4+reg
#pragma unroll
  for (int i = 0; i < 4; i++) {
    int mbase = rt * 128 + wm * 64 + i * 16 + kq * 4;
#pragma unroll
    for (int r = 0; r < 4; r++) {
      int m = mbase + r;
      if (m < cnt) {
        size_t hrow = (size_t)(r0 + m) * I_DIM + ct * 128 + wn * 64 + ml;
#pragma unroll
        for (int j = 0; j < 4; j++) {
          float g = accg[i][j][r];
          float u = accu[i][j][r];
          float s = g / (1.f + __expf(-g));
          h[hrow + j * 16] = f2bf_rne(s * u);
        }
      }
    }
  }
}

// ---------------- GEMM2: down proj + weighted atomic scatter ----------------
__global__ __launch_bounds__(256, 2) void gemm_down(
    const float* __restrict__ expert_down, const float* __restrict__ shared_down,
    const unsigned short* __restrict__ h,
    const int* __restrict__ row_token, const float* __restrict__ row_weight,
    const int* __restrict__ offsets, float* __restrict__ out) {
  int e = blockIdx.z;
  int r0 = offsets[e];
  int cnt = offsets[e + 1] - r0;
  int rt = blockIdx.y;
  if (rt * 128 >= cnt) return;
  int ct = blockIdx.x;  // 0..15 over D

  const float* downp = (e < NUM_EXPERTS) ? expert_down + (size_t)e * D_DIM * I_DIM : shared_down;

  __shared__ __align__(16) unsigned short As[128 * 32];
  __shared__ __align__(16) unsigned short Bs[128 * 32];

  int tid = threadIdx.x;
  int lane = tid & 63;
  int wave = tid >> 6;
  int wm = wave >> 1, wn = wave & 1;

  int arow0 = tid >> 2, seg = tid & 3;
  const unsigned short* ag0 = h + (size_t)(r0 + rt * 128 + arow0) * I_DIM + seg * 8;
  const unsigned short* ag1 = h + (size_t)(r0 + rt * 128 + 64 + arow0) * I_DIM + seg * 8;
  unsigned short* al0 = &As[tid * 8];
  unsigned short* al1 = &As[(256 + tid) * 8];

  const float* bp[4]; int bso[4];
#pragma unroll
  for (int j = 0; j < 4; j++) {
    int idxB = j * 256 + tid;
    int brow = idxB >> 3, c4 = idxB & 7;
    bp[j] = downp + (size_t)(ct * 128 + brow) * I_DIM + c4 * 4;
    bso[j] = brow * 32 + c4 * 4;
  }

  f32x4 acc[4][4];
  f32x4 zero4 = {0.f, 0.f, 0.f, 0.f};
#pragma unroll
  for (int i = 0; i < 4; i++)
#pragma unroll
    for (int j = 0; j < 4; j++) acc[i][j] = zero4;

  int kq = lane >> 4, ml = lane & 15;

  for (int k0 = 0; k0 < I_DIM; k0 += 32) {
    f32x4 vb[4];
#pragma unroll
    for (int j = 0; j < 4; j++) vb[j] = *(const f32x4*)(bp[j] + k0);
    __syncthreads();
    gload_lds16(ag0 + k0, al0);
    gload_lds16(ag1 + k0, al1);
#pragma unroll
    for (int j = 0; j < 4; j++) {
      const unsigned* ap = (const unsigned*)&vb[j];
      uint2 w;
      w.x = (ap[1] & 0xFFFF0000u) | (ap[0] >> 16);
      w.y = (ap[3] & 0xFFFF0000u) | (ap[2] >> 16);
      *(uint2*)&Bs[bso[j]] = w;
    }
    __syncthreads();

    short8 af[4];
#pragma unroll
    for (int i = 0; i < 4; i++)
      af[i] = *(const short8*)&As[(wm * 64 + i * 16 + ml) * 32 + kq * 8];
#pragma unroll
    for (int j = 0; j < 4; j++) {
      short8 bf = *(const short8*)&Bs[(wn * 64 + j * 16 + ml) * 32 + kq * 8];
#pragma unroll
      for (int i = 0; i < 4; i++)
        acc[i][j] = __builtin_amdgcn_mfma_f32_16x16x32_bf16(af[i], bf, acc[i][j], 0, 0, 0);
    }
  }

#pragma unroll
  for (int i = 0; i < 4; i++) {
    int mbase = rt * 128 + wm * 64 + i * 16 + kq * 4;
    int tkn[4]; float wv[4];
#pragma unroll
    for (int r = 0; r < 4; r++) {
      int m = mbase + r;
      bool v = (m < cnt);
      tkn[r] = v ? row_token[r0 + m] : 0;
      wv[r]  = v ? row_weight[r0 + m] : 0.f;
    }
#pragma unroll
    for (int j = 0; j < 4; j++) {
      int col = ct * 128 + wn * 64 + j * 16 + ml;
#pragma unroll
      for (int r = 0; r < 4; r++) {
        if (mbase + r < cnt)
          atomicAdd(&out[(size_t)tkn[r] * D_DIM + col], acc[i][j][r] * wv[r]);
      }
    }
  }
}

// ---------------- launch ----------------
extern "C" void kernel_launch(void* const* d_in, const int* in_sizes, int n_in,
                              void* d_out, int out_size, void* d_ws, size_t ws_size,
                              hipStream_t stream) {
  const float* x  = (const float*)d_in[0];
  const float* gw = (const float*)d_in[1];
  const float* eg = (const float*)d_in[2];
  const float* eu = (const float*)d_in[3];
  const float* ed = (const float*)d_in[4];
  const float* sg = (const float*)d_in[5];
  const float* su = (const float*)d_in[6];
  const float* sd = (const float*)d_in[7];
  float* out = (float*)d_out;

  char* ws = (char*)d_ws;
  int*   cnt       = (int*)(ws + 0);            // 16 ints
  float* probsum   = (float*)(ws + 64);         // 8 floats
  int*   offsets   = (int*)(ws + 128);          // 10 ints
  int*   top_e     = (int*)(ws + 256);
  int*   top_pos   = (int*)(ws + 256 + 65536);
  float* top_w     = (float*)(ws + 256 + 2 * 65536);
  int*   row_token = (int*)(ws + 256 + 3 * 65536);
  float* row_weight= (float*)(ws + 256 + 3 * 65536 + 98304);
  unsigned short* xb = (unsigned short*)(ws + 524288);
  unsigned short* h  = (unsigned short*)(ws + 524288 + (size_t)T_TOK * D_DIM * 2);
  // total workspace: 524288 + 33554432 + 276824064 = ~297 MB (assumed <= ws_size)

  hipMemsetAsync(ws, 0, 256, stream);                                  // cnt/probsum
  hipMemsetAsync(d_out, 0, (size_t)out_size * sizeof(float), stream);  // out accum

  xcvt_kernel<<<(T_TOK * D_DIM / 4) / 256, 256, 0, stream>>>(x, xb);
  router_kernel<<<T_TOK, 256, 0, stream>>>(x, gw, cnt, probsum, top_e, top_pos, top_w);
  finalize_kernel<<<1, 64, 0, stream>>>(cnt, probsum, offsets, out + (size_t)T_TOK * D_DIM);
  scatter_kernel<<<T_TOK / 256, 256, 0, stream>>>(top_e, top_pos, top_w, offsets,
                                                  row_token, row_weight);
  gemm_gateup<<<dim3(I_DIM / 128, 64, 9), 256, 0, stream>>>(eg, eu, sg, su, xb,
                                                            row_token, offsets, h);
  gemm_down<<<dim3(D_DIM / 128, 64, 9), 256, 0, stream>>>(ed, sd, h, row_token,
                                                          row_weight, offsets, out);
}